// Round 3
// baseline (9857.407 us; speedup 1.0000x reference)
//
#include <hip/hip_runtime.h>

typedef float v2f __attribute__((ext_vector_type(2)));

#define EPS 1e-5f
#define B 8
#define C 256
#define NPIX 4096      // 64*64
#define NCH 144        // rows: 0..63 q_bn, 64..127 v_bn, 128..143 kf(raw)
#define ROW_V 64
#define ROW_KF 128
#define PAD 11

// workspace layout (float offsets)
#define WP_OFF    0u          // Wt transposed: 256*144 = 36864
#define BIAS_OFF  36864u      // 144
#define PROJ_OFF  37120u      // 8*144*4096 = 4718592
#define RMAX_OFF  4755712u    // 128
#define RSC_OFF   4755840u    // 128
#define LC_OFF    4755968u    // 8*16*64 = 8192
#define ET_OFF    4764160u    // 529*16 = 8464

// ---------------- 1) fold BN into transposed projection weights Wt[c][144] ----------
__global__ __launch_bounds__(256) void k_wfold(
    const float* __restrict__ Wq, const float* __restrict__ qg, const float* __restrict__ qb,
    const float* __restrict__ qm, const float* __restrict__ qv,
    const float* __restrict__ Wk, const float* __restrict__ Wv,
    const float* __restrict__ vg, const float* __restrict__ vb,
    const float* __restrict__ vm, const float* __restrict__ vvar,
    float* __restrict__ Wt, float* __restrict__ biasp) {
  int o = blockIdx.x;   // 0..143
  int t = threadIdx.x;  // 0..255 = c
  const float* src; float s, bias;
  if (o < 64) {
    s = qg[o] * rsqrtf(qv[o] + EPS); bias = qb[o] - qm[o] * s; src = Wq + o * C;
  } else if (o < 128) {
    int i = o - 64;
    s = vg[i] * rsqrtf(vvar[i] + EPS); bias = vb[i] - vm[i] * s; src = Wv + i * C;
  } else {
    int i = o - 128; s = 1.f; bias = 0.f; src = Wk + i * C;
  }
  Wt[t * NCH + o] = src[t] * s;   // transposed: c-major rows of 144
  if (t == 0) biasp[o] = bias;
}

// ---------------- 1b) transpose embedding: et[tap][k] ----------
__global__ __launch_bounds__(256) void k_etrans(
    const float* __restrict__ emb, float* __restrict__ et) {
  int i = blockIdx.x * 256 + threadIdx.x;   // 0..8463
  if (i < 529 * 16) {
    int tap = i / 16, k = i % 16;
    et[i] = emb[k * 529 + tap];
  }
}

// ---------------- 2) projection GEMM: proj[b][o][n] = sum_c Wt[c][o] x[b][c][n] + b'[o] ----
__global__ __launch_bounds__(256) void k_proj(
    const float* __restrict__ x, const float* __restrict__ Wt,
    const float* __restrict__ biasp, float* __restrict__ proj) {
  int g = blockIdx.x;     // 0..2 (48 ch each)
  int tile = blockIdx.y;  // 0..15 (256 px each)
  int b = blockIdx.z;
  int t = threadIdx.x;
  int px = tile * 256 + t;
  const float* xb = x + (size_t)b * C * NPIX + px;
  float acc[48];
  #pragma unroll
  for (int i = 0; i < 48; i++) acc[i] = 0.f;
  #pragma unroll 2
  for (int c = 0; c < C; c++) {
    float xv = xb[(size_t)c * NPIX];
    const float* wrow = Wt + c * NCH + g * 48;   // uniform -> s_load
    #pragma unroll
    for (int i = 0; i < 48; i++) acc[i] += xv * wrow[i];
  }
  float* ob = proj + ((size_t)b * NCH + g * 48) * NPIX + px;
  #pragma unroll
  for (int i = 0; i < 48; i++) ob[(size_t)i * NPIX] = acc[i] + biasp[g * 48 + i];
}

// ---------------- 3) softmax row stats for kf rows ----------------
__global__ __launch_bounds__(256) void k_softstat(
    const float* __restrict__ proj, float* __restrict__ rmax, float* __restrict__ rsc) {
  int k = blockIdx.x, b = blockIdx.y, t = threadIdx.x;
  const float* row = proj + ((size_t)b * NCH + ROW_KF + k) * NPIX;
  __shared__ float sd[256];
  float m = -1e30f;
  for (int n = t; n < NPIX; n += 256) m = fmaxf(m, row[n]);
  sd[t] = m; __syncthreads();
  for (int s = 128; s > 0; s >>= 1) { if (t < s) sd[t] = fmaxf(sd[t], sd[t + s]); __syncthreads(); }
  m = sd[0]; __syncthreads();
  float sum = 0.f;
  for (int n = t; n < NPIX; n += 256) sum += __expf(row[n] - m);
  sd[t] = sum; __syncthreads();
  for (int s = 128; s > 0; s >>= 1) { if (t < s) sd[t] += sd[t + s]; __syncthreads(); }
  if (t == 0) { rmax[b * 16 + k] = m; rsc[b * 16 + k] = 1.f / sd[0]; }
}

// ---------------- 4) lambda_c partial: 8 n-chunks, atomicAdd into zeroed lc ----------
__global__ __launch_bounds__(256) void k_lambda_c(
    const float* __restrict__ proj, const float* __restrict__ rmax,
    const float* __restrict__ rsc, float* __restrict__ lc) {
  int k = blockIdx.x, chunk = blockIdx.y, b = blockIdx.z, t = threadIdx.x;
  const float* row = proj + ((size_t)b * NCH + ROW_KF + k) * NPIX;
  const float* vbase = proj + ((size_t)b * NCH + ROW_V) * NPIX;
  float m = rmax[b * 16 + k], sc = rsc[b * 16 + k];
  float acc[64];
  #pragma unroll
  for (int i = 0; i < 64; i++) acc[i] = 0.f;
  for (int it = 0; it < 2; ++it) {
    int n = chunk * 512 + it * 256 + t;
    float p = __expf(row[n] - m) * sc;
    #pragma unroll
    for (int vv = 0; vv < 64; vv++) acc[vv] += p * vbase[(size_t)vv * NPIX + n];
  }
  int lane = t & 63, wid = t >> 6;
  float keep = 0.f;
  #pragma unroll
  for (int vv = 0; vv < 64; vv++) {
    float s = acc[vv];
    #pragma unroll
    for (int off = 32; off > 0; off >>= 1) s += __shfl_xor(s, off);
    if (lane == vv) keep = s;
  }
  __shared__ float sh[4 * 64];
  sh[wid * 64 + lane] = keep;
  __syncthreads();
  if (t < 64) {
    float val = sh[t] + sh[64 + t] + sh[128 + t] + sh[192 + t];
    atomicAdd(&lc[((size_t)b * 16 + k) * 64 + t], val);
  }
}

// ---------------- 5) fused 23x23 conv + k-contraction with q + y_c -----------
// E in LDS as packed-bf16 pairs (2 x ds_read_b128 per tap); vh via 8-row rolling
// register window, ky inner (1 new ds_read_b32 per tap). float2 accumulators
// paired along k so ffp-contract can emit v_pk_fma_f32.
#define VH_PITCH 88
#define VH_ROWS 54
__global__ __launch_bounds__(256) void k_conv_fused(
    const float* __restrict__ proj, const float* __restrict__ et,
    const float* __restrict__ lc, float* __restrict__ out) {
  int v = blockIdx.x;     // 0..63 (fastest: blocks sharing (b,tile) reuse q via L2)
  int tile = blockIdx.y;  // 0..1 (32 image rows each)
  int b = blockIdx.z;
  int t = threadIdx.x;
  __shared__ float vh[VH_ROWS * VH_PITCH];       // 19008 B
  __shared__ unsigned int ebf[529 * 8];          // 16928 B: [tap][kpair] packed bf16

  // stage E: ebf[tap*8+j] = bf16(E[2j]) | bf16(E[2j+1])<<16   (RNE rounding)
  for (int i = t; i < 529 * 8; i += 256) {
    int tap = i >> 3, j = i & 7;
    unsigned int u0 = __float_as_uint(et[tap * 16 + 2 * j]);
    unsigned int u1 = __float_as_uint(et[tap * 16 + 2 * j + 1]);
    u0 = (u0 + 0x7fffu + ((u0 >> 16) & 1u)) >> 16;
    u1 = (u1 + 0x7fffu + ((u1 >> 16) & 1u)) & 0xffff0000u;
    ebf[i] = u0 | u1;
  }
  int r0g = tile * 32;
  const float* vrow = proj + ((size_t)b * NCH + ROW_V + v) * NPIX;
  for (int i = t; i < VH_ROWS * 86; i += 256) {
    int r = i / 86, cc = i % 86;
    int gr = r0g + r - PAD, gc = cc - PAD;
    float val = 0.f;
    if (gr >= 0 && gr < 64 && gc >= 0 && gc < 64) val = vrow[gr * 64 + gc];
    vh[r * VH_PITCH + cc] = val;
  }
  __syncthreads();

  int col = t & 63, wid = t >> 6;
  int rb = wid * 8;                         // wave's first output row within tile
  v2f lp2[8][8];                            // [kpair][row]
  #pragma unroll
  for (int j = 0; j < 8; j++)
    #pragma unroll
    for (int i = 0; i < 8; i++) { lp2[j][i].x = 0.f; lp2[j][i].y = 0.f; }

  #pragma unroll 1
  for (int kx = 0; kx < 23; kx++) {
    const float* wp = vh + rb * VH_PITCH + (col + kx);
    float w[8];
    #pragma unroll
    for (int i = 0; i < 8; i++) w[i] = wp[i * VH_PITCH];
    #pragma unroll
    for (int ky = 0; ky < 23; ky++) {
      const uint4* ep = (const uint4*)&ebf[(ky * 23 + kx) * 8];
      uint4 ea = ep[0];
      uint4 eb = ep[1];
      float wn = (ky < 22) ? wp[(8 + ky) * VH_PITCH] : 0.f;   // prefetch next row
      v2f e2[8];
      e2[0].x = __uint_as_float(ea.x << 16); e2[0].y = __uint_as_float(ea.x & 0xffff0000u);
      e2[1].x = __uint_as_float(ea.y << 16); e2[1].y = __uint_as_float(ea.y & 0xffff0000u);
      e2[2].x = __uint_as_float(ea.z << 16); e2[2].y = __uint_as_float(ea.z & 0xffff0000u);
      e2[3].x = __uint_as_float(ea.w << 16); e2[3].y = __uint_as_float(ea.w & 0xffff0000u);
      e2[4].x = __uint_as_float(eb.x << 16); e2[4].y = __uint_as_float(eb.x & 0xffff0000u);
      e2[5].x = __uint_as_float(eb.y << 16); e2[5].y = __uint_as_float(eb.y & 0xffff0000u);
      e2[6].x = __uint_as_float(eb.z << 16); e2[6].y = __uint_as_float(eb.z & 0xffff0000u);
      e2[7].x = __uint_as_float(eb.w << 16); e2[7].y = __uint_as_float(eb.w & 0xffff0000u);
      #pragma unroll
      for (int i = 0; i < 8; i++) {
        v2f wpair; wpair.x = w[i]; wpair.y = w[i];
        #pragma unroll
        for (int j = 0; j < 8; j++) lp2[j][i] += e2[j] * wpair;
      }
      #pragma unroll
      for (int i = 0; i < 7; i++) w[i] = w[i + 1];
      w[7] = wn;
    }
  }

  float lcv[16];
  #pragma unroll
  for (int k = 0; k < 16; k++) lcv[k] = lc[((size_t)b * 16 + k) * 64 + v];  // uniform
  const float* qbp = proj + (size_t)b * NCH * NPIX;
  float* ob = out + (size_t)b * 256 * NPIX;
  #pragma unroll 1
  for (int i = 0; i < 8; i++) {
    int n = (r0g + rb + i) * 64 + col;
    float lam[16];
    #pragma unroll
    for (int j = 0; j < 8; j++) {
      lam[2 * j]     = lp2[j][i].x + lcv[2 * j];
      lam[2 * j + 1] = lp2[j][i].y + lcv[2 * j + 1];
    }
    float y0 = 0.f, y1 = 0.f, y2 = 0.f, y3 = 0.f;
    #pragma unroll
    for (int k = 0; k < 16; k++) {
      float mz = lam[k];
      y0 += qbp[(size_t)(0 * 16 + k) * NPIX + n] * mz;
      y1 += qbp[(size_t)(1 * 16 + k) * NPIX + n] * mz;
      y2 += qbp[(size_t)(2 * 16 + k) * NPIX + n] * mz;
      y3 += qbp[(size_t)(3 * 16 + k) * NPIX + n] * mz;
    }
    ob[(size_t)(0 * 64 + v) * NPIX + n] = y0;
    ob[(size_t)(1 * 64 + v) * NPIX + n] = y1;
    ob[(size_t)(2 * 64 + v) * NPIX + n] = y2;
    ob[(size_t)(3 * 64 + v) * NPIX + n] = y3;
  }
}

extern "C" void kernel_launch(void* const* d_in, const int* in_sizes, int n_in,
                              void* d_out, int out_size, void* d_ws, size_t ws_size,
                              hipStream_t stream) {
  const float* x    = (const float*)d_in[0];
  const float* Wq   = (const float*)d_in[1];
  const float* qg   = (const float*)d_in[2];
  const float* qbta = (const float*)d_in[3];
  const float* qm   = (const float*)d_in[4];
  const float* qv   = (const float*)d_in[5];
  const float* Wk   = (const float*)d_in[6];
  const float* Wv   = (const float*)d_in[7];
  const float* vg   = (const float*)d_in[8];
  const float* vb   = (const float*)d_in[9];
  const float* vm   = (const float*)d_in[10];
  const float* vvar = (const float*)d_in[11];
  const float* emb  = (const float*)d_in[12];
  float* ws   = (float*)d_ws;
  float* Wt   = ws + WP_OFF;
  float* bp   = ws + BIAS_OFF;
  float* proj = ws + PROJ_OFF;
  float* rmax = ws + RMAX_OFF;
  float* rsc  = ws + RSC_OFF;
  float* lcw  = ws + LC_OFF;
  float* etw  = ws + ET_OFF;
  float* out  = (float*)d_out;

  hipLaunchKernelGGL(k_wfold, dim3(144), dim3(256), 0, stream,
                     Wq, qg, qbta, qm, qv, Wk, Wv, vg, vb, vm, vvar, Wt, bp);
  hipLaunchKernelGGL(k_etrans, dim3(34), dim3(256), 0, stream, emb, etw);
  hipMemsetAsync(lcw, 0, 16 * 64 * B * sizeof(float), stream);
  hipLaunchKernelGGL(k_proj, dim3(3, 16, 8), dim3(256), 0, stream, x, Wt, bp, proj);
  hipLaunchKernelGGL(k_softstat, dim3(16, 8), dim3(256), 0, stream, proj, rmax, rsc);
  hipLaunchKernelGGL(k_lambda_c, dim3(16, 8, 8), dim3(256), 0, stream, proj, rmax, rsc, lcw);
  hipLaunchKernelGGL(k_conv_fused, dim3(64, 2, 8), dim3(256), 0, stream, proj, etw, lcw, out);
}

// Round 4
// 9727.697 us; speedup vs baseline: 1.0133x; 1.0133x over previous
//
#include <hip/hip_runtime.h>

typedef float v2f __attribute__((ext_vector_type(2)));

#define EPS 1e-5f
#define B 8
#define C 256
#define NPIX 4096      // 64*64
#define NCH 144        // rows: 0..63 q_bn, 64..127 v_bn, 128..143 kf(raw)
#define ROW_V 64
#define ROW_KF 128
#define PAD 11

// workspace layout (float offsets)
#define WP_OFF    0u          // Wt transposed: 256*144 = 36864
#define BIAS_OFF  36864u      // 144
#define PROJ_OFF  37120u      // 8*144*4096 = 4718592
#define RMAX_OFF  4755712u    // 128
#define RSC_OFF   4755840u    // 128
#define LC_OFF    4755968u    // 8*16*64 = 8192
#define ET_OFF    4764160u    // 529*16 = 8464

// ---------------- 1) fold BN into transposed projection weights Wt[c][144] ----------
__global__ __launch_bounds__(256) void k_wfold(
    const float* __restrict__ Wq, const float* __restrict__ qg, const float* __restrict__ qb,
    const float* __restrict__ qm, const float* __restrict__ qv,
    const float* __restrict__ Wk, const float* __restrict__ Wv,
    const float* __restrict__ vg, const float* __restrict__ vb,
    const float* __restrict__ vm, const float* __restrict__ vvar,
    float* __restrict__ Wt, float* __restrict__ biasp) {
  int o = blockIdx.x;   // 0..143
  int t = threadIdx.x;  // 0..255 = c
  const float* src; float s, bias;
  if (o < 64) {
    s = qg[o] * rsqrtf(qv[o] + EPS); bias = qb[o] - qm[o] * s; src = Wq + o * C;
  } else if (o < 128) {
    int i = o - 64;
    s = vg[i] * rsqrtf(vvar[i] + EPS); bias = vb[i] - vm[i] * s; src = Wv + i * C;
  } else {
    int i = o - 128; s = 1.f; bias = 0.f; src = Wk + i * C;
  }
  Wt[t * NCH + o] = src[t] * s;   // transposed: c-major rows of 144
  if (t == 0) biasp[o] = bias;
}

// ---------------- 1b) transpose embedding: et[tap][k] ----------
__global__ __launch_bounds__(256) void k_etrans(
    const float* __restrict__ emb, float* __restrict__ et) {
  int i = blockIdx.x * 256 + threadIdx.x;   // 0..8463
  if (i < 529 * 16) {
    int tap = i / 16, k = i % 16;
    et[i] = emb[k * 529 + tap];
  }
}

// ---------------- 2) projection GEMM: proj[b][o][n] = sum_c Wt[c][o] x[b][c][n] + b'[o] ----
__global__ __launch_bounds__(256) void k_proj(
    const float* __restrict__ x, const float* __restrict__ Wt,
    const float* __restrict__ biasp, float* __restrict__ proj) {
  int g = blockIdx.x;     // 0..2 (48 ch each)
  int tile = blockIdx.y;  // 0..15 (256 px each)
  int b = blockIdx.z;
  int t = threadIdx.x;
  int px = tile * 256 + t;
  const float* xb = x + (size_t)b * C * NPIX + px;
  float acc[48];
  #pragma unroll
  for (int i = 0; i < 48; i++) acc[i] = 0.f;
  #pragma unroll 2
  for (int c = 0; c < C; c++) {
    float xv = xb[(size_t)c * NPIX];
    const float* wrow = Wt + c * NCH + g * 48;   // uniform -> s_load
    #pragma unroll
    for (int i = 0; i < 48; i++) acc[i] += xv * wrow[i];
  }
  float* ob = proj + ((size_t)b * NCH + g * 48) * NPIX + px;
  #pragma unroll
  for (int i = 0; i < 48; i++) ob[(size_t)i * NPIX] = acc[i] + biasp[g * 48 + i];
}

// ---------------- 3) softmax row stats for kf rows ----------------
__global__ __launch_bounds__(256) void k_softstat(
    const float* __restrict__ proj, float* __restrict__ rmax, float* __restrict__ rsc) {
  int k = blockIdx.x, b = blockIdx.y, t = threadIdx.x;
  const float* row = proj + ((size_t)b * NCH + ROW_KF + k) * NPIX;
  __shared__ float sd[256];
  float m = -1e30f;
  for (int n = t; n < NPIX; n += 256) m = fmaxf(m, row[n]);
  sd[t] = m; __syncthreads();
  for (int s = 128; s > 0; s >>= 1) { if (t < s) sd[t] = fmaxf(sd[t], sd[t + s]); __syncthreads(); }
  m = sd[0]; __syncthreads();
  float sum = 0.f;
  for (int n = t; n < NPIX; n += 256) sum += __expf(row[n] - m);
  sd[t] = sum; __syncthreads();
  for (int s = 128; s > 0; s >>= 1) { if (t < s) sd[t] += sd[t + s]; __syncthreads(); }
  if (t == 0) { rmax[b * 16 + k] = m; rsc[b * 16 + k] = 1.f / sd[0]; }
}

// ---------------- 4) lambda_c partial: 8 n-chunks, atomicAdd into zeroed lc ----------
__global__ __launch_bounds__(256) void k_lambda_c(
    const float* __restrict__ proj, const float* __restrict__ rmax,
    const float* __restrict__ rsc, float* __restrict__ lc) {
  int k = blockIdx.x, chunk = blockIdx.y, b = blockIdx.z, t = threadIdx.x;
  const float* row = proj + ((size_t)b * NCH + ROW_KF + k) * NPIX;
  const float* vbase = proj + ((size_t)b * NCH + ROW_V) * NPIX;
  float m = rmax[b * 16 + k], sc = rsc[b * 16 + k];
  float acc[64];
  #pragma unroll
  for (int i = 0; i < 64; i++) acc[i] = 0.f;
  for (int it = 0; it < 2; ++it) {
    int n = chunk * 512 + it * 256 + t;
    float p = __expf(row[n] - m) * sc;
    #pragma unroll
    for (int vv = 0; vv < 64; vv++) acc[vv] += p * vbase[(size_t)vv * NPIX + n];
  }
  int lane = t & 63, wid = t >> 6;
  float keep = 0.f;
  #pragma unroll
  for (int vv = 0; vv < 64; vv++) {
    float s = acc[vv];
    #pragma unroll
    for (int off = 32; off > 0; off >>= 1) s += __shfl_xor(s, off);
    if (lane == vv) keep = s;
  }
  __shared__ float sh[4 * 64];
  sh[wid * 64 + lane] = keep;
  __syncthreads();
  if (t < 64) {
    float val = sh[t] + sh[64 + t] + sh[128 + t] + sh[192 + t];
    atomicAdd(&lc[((size_t)b * 16 + k) * 64 + t], val);
  }
}

// ---------------- 5) fused 23x23 conv + k-contraction with q + y_c -----------
// E in LDS as packed-bf16 pairs (2 x ds_read_b128 per tap); vh via 8-row rolling
// register window, ky inner (1 new ds_read_b32 per tap). float2 accumulators
// paired along k so ffp-contract can emit v_pk_fma_f32.
// __launch_bounds__(256, 2): min 2 waves/EU -> 256-VGPR cap. Accumulators are
// 128 VGPRs; without this the allocator targeted ~112 VGPRs and spilled the
// whole acc file to scratch (R3: 66 GB scratch traffic, 9.5 ms).
#define VH_PITCH 88
#define VH_ROWS 54
__global__ __launch_bounds__(256, 2) void k_conv_fused(
    const float* __restrict__ proj, const float* __restrict__ et,
    const float* __restrict__ lc, float* __restrict__ out) {
  int v = blockIdx.x;     // 0..63 (fastest: blocks sharing (b,tile) reuse q via L2)
  int tile = blockIdx.y;  // 0..1 (32 image rows each)
  int b = blockIdx.z;
  int t = threadIdx.x;
  __shared__ float vh[VH_ROWS * VH_PITCH];       // 19008 B
  __shared__ unsigned int ebf[529 * 8];          // 16928 B: [tap][kpair] packed bf16

  // stage E: ebf[tap*8+j] = bf16(E[2j]) | bf16(E[2j+1])<<16   (RNE rounding)
  for (int i = t; i < 529 * 8; i += 256) {
    int tap = i >> 3, j = i & 7;
    unsigned int u0 = __float_as_uint(et[tap * 16 + 2 * j]);
    unsigned int u1 = __float_as_uint(et[tap * 16 + 2 * j + 1]);
    u0 = (u0 + 0x7fffu + ((u0 >> 16) & 1u)) >> 16;
    u1 = (u1 + 0x7fffu + ((u1 >> 16) & 1u)) & 0xffff0000u;
    ebf[i] = u0 | u1;
  }
  int r0g = tile * 32;
  const float* vrow = proj + ((size_t)b * NCH + ROW_V + v) * NPIX;
  for (int i = t; i < VH_ROWS * 86; i += 256) {
    int r = i / 86, cc = i % 86;
    int gr = r0g + r - PAD, gc = cc - PAD;
    float val = 0.f;
    if (gr >= 0 && gr < 64 && gc >= 0 && gc < 64) val = vrow[gr * 64 + gc];
    vh[r * VH_PITCH + cc] = val;
  }
  __syncthreads();

  int col = t & 63, wid = t >> 6;
  int rb = wid * 8;                         // wave's first output row within tile
  v2f lp2[8][8];                            // [kpair][row]
  #pragma unroll
  for (int j = 0; j < 8; j++)
    #pragma unroll
    for (int i = 0; i < 8; i++) { lp2[j][i].x = 0.f; lp2[j][i].y = 0.f; }

  #pragma unroll 1
  for (int kx = 0; kx < 23; kx++) {
    const float* wp = vh + rb * VH_PITCH + (col + kx);
    float w[8];
    #pragma unroll
    for (int i = 0; i < 8; i++) w[i] = wp[i * VH_PITCH];
    #pragma unroll
    for (int ky = 0; ky < 23; ky++) {
      const uint4* ep = (const uint4*)&ebf[(ky * 23 + kx) * 8];
      uint4 ea = ep[0];
      uint4 eb = ep[1];
      float wn = (ky < 22) ? wp[(8 + ky) * VH_PITCH] : 0.f;   // prefetch next row
      v2f e2[8];
      e2[0].x = __uint_as_float(ea.x << 16); e2[0].y = __uint_as_float(ea.x & 0xffff0000u);
      e2[1].x = __uint_as_float(ea.y << 16); e2[1].y = __uint_as_float(ea.y & 0xffff0000u);
      e2[2].x = __uint_as_float(ea.z << 16); e2[2].y = __uint_as_float(ea.z & 0xffff0000u);
      e2[3].x = __uint_as_float(ea.w << 16); e2[3].y = __uint_as_float(ea.w & 0xffff0000u);
      e2[4].x = __uint_as_float(eb.x << 16); e2[4].y = __uint_as_float(eb.x & 0xffff0000u);
      e2[5].x = __uint_as_float(eb.y << 16); e2[5].y = __uint_as_float(eb.y & 0xffff0000u);
      e2[6].x = __uint_as_float(eb.z << 16); e2[6].y = __uint_as_float(eb.z & 0xffff0000u);
      e2[7].x = __uint_as_float(eb.w << 16); e2[7].y = __uint_as_float(eb.w & 0xffff0000u);
      #pragma unroll
      for (int i = 0; i < 8; i++) {
        v2f wpair; wpair.x = w[i]; wpair.y = w[i];
        #pragma unroll
        for (int j = 0; j < 8; j++) lp2[j][i] += e2[j] * wpair;
      }
      #pragma unroll
      for (int i = 0; i < 7; i++) w[i] = w[i + 1];
      w[7] = wn;
    }
  }

  float lcv[16];
  #pragma unroll
  for (int k = 0; k < 16; k++) lcv[k] = lc[((size_t)b * 16 + k) * 64 + v];  // uniform
  const float* qbp = proj + (size_t)b * NCH * NPIX;
  float* ob = out + (size_t)b * 256 * NPIX;
  #pragma unroll 1
  for (int i = 0; i < 8; i++) {
    int n = (r0g + rb + i) * 64 + col;
    float lam[16];
    #pragma unroll
    for (int j = 0; j < 8; j++) {
      lam[2 * j]     = lp2[j][i].x + lcv[2 * j];
      lam[2 * j + 1] = lp2[j][i].y + lcv[2 * j + 1];
    }
    float y0 = 0.f, y1 = 0.f, y2 = 0.f, y3 = 0.f;
    #pragma unroll
    for (int k = 0; k < 16; k++) {
      float mz = lam[k];
      y0 += qbp[(size_t)(0 * 16 + k) * NPIX + n] * mz;
      y1 += qbp[(size_t)(1 * 16 + k) * NPIX + n] * mz;
      y2 += qbp[(size_t)(2 * 16 + k) * NPIX + n] * mz;
      y3 += qbp[(size_t)(3 * 16 + k) * NPIX + n] * mz;
    }
    ob[(size_t)(0 * 64 + v) * NPIX + n] = y0;
    ob[(size_t)(1 * 64 + v) * NPIX + n] = y1;
    ob[(size_t)(2 * 64 + v) * NPIX + n] = y2;
    ob[(size_t)(3 * 64 + v) * NPIX + n] = y3;
  }
}

extern "C" void kernel_launch(void* const* d_in, const int* in_sizes, int n_in,
                              void* d_out, int out_size, void* d_ws, size_t ws_size,
                              hipStream_t stream) {
  const float* x    = (const float*)d_in[0];
  const float* Wq   = (const float*)d_in[1];
  const float* qg   = (const float*)d_in[2];
  const float* qbta = (const float*)d_in[3];
  const float* qm   = (const float*)d_in[4];
  const float* qv   = (const float*)d_in[5];
  const float* Wk   = (const float*)d_in[6];
  const float* Wv   = (const float*)d_in[7];
  const float* vg   = (const float*)d_in[8];
  const float* vb   = (const float*)d_in[9];
  const float* vm   = (const float*)d_in[10];
  const float* vvar = (const float*)d_in[11];
  const float* emb  = (const float*)d_in[12];
  float* ws   = (float*)d_ws;
  float* Wt   = ws + WP_OFF;
  float* bp   = ws + BIAS_OFF;
  float* proj = ws + PROJ_OFF;
  float* rmax = ws + RMAX_OFF;
  float* rsc  = ws + RSC_OFF;
  float* lcw  = ws + LC_OFF;
  float* etw  = ws + ET_OFF;
  float* out  = (float*)d_out;

  hipLaunchKernelGGL(k_wfold, dim3(144), dim3(256), 0, stream,
                     Wq, qg, qbta, qm, qv, Wk, Wv, vg, vb, vm, vvar, Wt, bp);
  hipLaunchKernelGGL(k_etrans, dim3(34), dim3(256), 0, stream, emb, etw);
  hipMemsetAsync(lcw, 0, 16 * 64 * B * sizeof(float), stream);
  hipLaunchKernelGGL(k_proj, dim3(3, 16, 8), dim3(256), 0, stream, x, Wt, bp, proj);
  hipLaunchKernelGGL(k_softstat, dim3(16, 8), dim3(256), 0, stream, proj, rmax, rsc);
  hipLaunchKernelGGL(k_lambda_c, dim3(16, 8, 8), dim3(256), 0, stream, proj, rmax, rsc, lcw);
  hipLaunchKernelGGL(k_conv_fused, dim3(64, 2, 8), dim3(256), 0, stream, proj, etw, lcw, out);
}

// Round 5
// 775.804 us; speedup vs baseline: 12.7061x; 12.5389x over previous
//
#include <hip/hip_runtime.h>

typedef float v2f __attribute__((ext_vector_type(2)));

#define EPS 1e-5f
#define B 8
#define C 256
#define NPIX 4096      // 64*64
#define NCH 144        // rows: 0..63 q_bn, 64..127 v_bn, 128..143 kf(raw)
#define ROW_V 64
#define ROW_KF 128
#define PAD 11

// workspace layout (float offsets)
#define WP_OFF    0u          // Wt transposed: 256*144 = 36864
#define BIAS_OFF  36864u      // 144
#define PROJ_OFF  37120u      // 8*144*4096 = 4718592
#define RMAX_OFF  4755712u    // 128
#define RSC_OFF   4755840u    // 128
#define LC_OFF    4755968u    // 8*16*64 = 8192
#define ET_OFF    4764160u    // 529*16 = 8464

// ---------------- 1) fold BN into transposed projection weights Wt[c][144] ----------
__global__ __launch_bounds__(256) void k_wfold(
    const float* __restrict__ Wq, const float* __restrict__ qg, const float* __restrict__ qb,
    const float* __restrict__ qm, const float* __restrict__ qv,
    const float* __restrict__ Wk, const float* __restrict__ Wv,
    const float* __restrict__ vg, const float* __restrict__ vb,
    const float* __restrict__ vm, const float* __restrict__ vvar,
    float* __restrict__ Wt, float* __restrict__ biasp) {
  int o = blockIdx.x;   // 0..143
  int t = threadIdx.x;  // 0..255 = c
  const float* src; float s, bias;
  if (o < 64) {
    s = qg[o] * rsqrtf(qv[o] + EPS); bias = qb[o] - qm[o] * s; src = Wq + o * C;
  } else if (o < 128) {
    int i = o - 64;
    s = vg[i] * rsqrtf(vvar[i] + EPS); bias = vb[i] - vm[i] * s; src = Wv + i * C;
  } else {
    int i = o - 128; s = 1.f; bias = 0.f; src = Wk + i * C;
  }
  Wt[t * NCH + o] = src[t] * s;   // transposed: c-major rows of 144
  if (t == 0) biasp[o] = bias;
}

// ---------------- 1b) transpose embedding: et[tap][k] ----------
__global__ __launch_bounds__(256) void k_etrans(
    const float* __restrict__ emb, float* __restrict__ et) {
  int i = blockIdx.x * 256 + threadIdx.x;   // 0..8463
  if (i < 529 * 16) {
    int tap = i / 16, k = i % 16;
    et[i] = emb[k * 529 + tap];
  }
}

// ---------------- 2) projection GEMM: proj[b][o][n] = sum_c Wt[c][o] x[b][c][n] + b'[o] ----
__global__ __launch_bounds__(256) void k_proj(
    const float* __restrict__ x, const float* __restrict__ Wt,
    const float* __restrict__ biasp, float* __restrict__ proj) {
  int g = blockIdx.x;     // 0..2 (48 ch each)
  int tile = blockIdx.y;  // 0..15 (256 px each)
  int b = blockIdx.z;
  int t = threadIdx.x;
  int px = tile * 256 + t;
  const float* xb = x + (size_t)b * C * NPIX + px;
  float acc[48];
  #pragma unroll
  for (int i = 0; i < 48; i++) acc[i] = 0.f;
  #pragma unroll 2
  for (int c = 0; c < C; c++) {
    float xv = xb[(size_t)c * NPIX];
    const float* wrow = Wt + c * NCH + g * 48;   // uniform -> s_load
    #pragma unroll
    for (int i = 0; i < 48; i++) acc[i] += xv * wrow[i];
  }
  float* ob = proj + ((size_t)b * NCH + g * 48) * NPIX + px;
  #pragma unroll
  for (int i = 0; i < 48; i++) ob[(size_t)i * NPIX] = acc[i] + biasp[g * 48 + i];
}

// ---------------- 3) softmax row stats for kf rows ----------------
__global__ __launch_bounds__(256) void k_softstat(
    const float* __restrict__ proj, float* __restrict__ rmax, float* __restrict__ rsc) {
  int k = blockIdx.x, b = blockIdx.y, t = threadIdx.x;
  const float* row = proj + ((size_t)b * NCH + ROW_KF + k) * NPIX;
  __shared__ float sd[256];
  float m = -1e30f;
  for (int n = t; n < NPIX; n += 256) m = fmaxf(m, row[n]);
  sd[t] = m; __syncthreads();
  for (int s = 128; s > 0; s >>= 1) { if (t < s) sd[t] = fmaxf(sd[t], sd[t + s]); __syncthreads(); }
  m = sd[0]; __syncthreads();
  float sum = 0.f;
  for (int n = t; n < NPIX; n += 256) sum += __expf(row[n] - m);
  sd[t] = sum; __syncthreads();
  for (int s = 128; s > 0; s >>= 1) { if (t < s) sd[t] += sd[t + s]; __syncthreads(); }
  if (t == 0) { rmax[b * 16 + k] = m; rsc[b * 16 + k] = 1.f / sd[0]; }
}

// ---------------- 4) lambda_c partial: 8 n-chunks, atomicAdd into zeroed lc ----------
__global__ __launch_bounds__(256) void k_lambda_c(
    const float* __restrict__ proj, const float* __restrict__ rmax,
    const float* __restrict__ rsc, float* __restrict__ lc) {
  int k = blockIdx.x, chunk = blockIdx.y, b = blockIdx.z, t = threadIdx.x;
  const float* row = proj + ((size_t)b * NCH + ROW_KF + k) * NPIX;
  const float* vbase = proj + ((size_t)b * NCH + ROW_V) * NPIX;
  float m = rmax[b * 16 + k], sc = rsc[b * 16 + k];
  float acc[64];
  #pragma unroll
  for (int i = 0; i < 64; i++) acc[i] = 0.f;
  for (int it = 0; it < 2; ++it) {
    int n = chunk * 512 + it * 256 + t;
    float p = __expf(row[n] - m) * sc;
    #pragma unroll
    for (int vv = 0; vv < 64; vv++) acc[vv] += p * vbase[(size_t)vv * NPIX + n];
  }
  int lane = t & 63, wid = t >> 6;
  float keep = 0.f;
  #pragma unroll
  for (int vv = 0; vv < 64; vv++) {
    float s = acc[vv];
    #pragma unroll
    for (int off = 32; off > 0; off >>= 1) s += __shfl_xor(s, off);
    if (lane == vv) keep = s;
  }
  __shared__ float sh[4 * 64];
  sh[wid * 64 + lane] = keep;
  __syncthreads();
  if (t < 64) {
    float val = sh[t] + sh[64 + t] + sh[128 + t] + sh[192 + t];
    atomicAdd(&lc[((size_t)b * 16 + k) * 64 + t], val);
  }
}

// ---------------- 5) fused 23x23 conv + k-contraction with q + y_c -----------
// E in LDS as packed-bf16 pairs (2 x ds_read_b128 per tap); vh via 8-row rolling
// register window, ky inner (1 new ds_read_b32 per tap).
// CRITICAL: every loop touching lp2[][] must be FULLY UNROLLED (constant
// indices). R3/R4 had `#pragma unroll 1` on the epilogue -> dynamic indexing
// -> lp2 demoted to scratch -> 66 GB of scratch traffic and 9.5 ms.
#define VH_PITCH 88
#define VH_ROWS 54
__global__ __launch_bounds__(256, 2) void k_conv_fused(
    const float* __restrict__ proj, const float* __restrict__ et,
    const float* __restrict__ lc, float* __restrict__ out) {
  int v = blockIdx.x;     // 0..63 (fastest: blocks sharing (b,tile) reuse q via L2)
  int tile = blockIdx.y;  // 0..1 (32 image rows each)
  int b = blockIdx.z;
  int t = threadIdx.x;
  __shared__ float vh[VH_ROWS * VH_PITCH];       // 19008 B
  __shared__ unsigned int ebf[529 * 8];          // 16928 B: [tap][kpair] packed bf16

  // stage E: ebf[tap*8+j] = bf16(E[2j]) | bf16(E[2j+1])<<16   (RNE rounding)
  for (int i = t; i < 529 * 8; i += 256) {
    int tap = i >> 3, j = i & 7;
    unsigned int u0 = __float_as_uint(et[tap * 16 + 2 * j]);
    unsigned int u1 = __float_as_uint(et[tap * 16 + 2 * j + 1]);
    u0 = (u0 + 0x7fffu + ((u0 >> 16) & 1u)) >> 16;
    u1 = (u1 + 0x7fffu + ((u1 >> 16) & 1u)) & 0xffff0000u;
    ebf[i] = u0 | u1;
  }
  int r0g = tile * 32;
  const float* vrow = proj + ((size_t)b * NCH + ROW_V + v) * NPIX;
  for (int i = t; i < VH_ROWS * 86; i += 256) {
    int r = i / 86, cc = i % 86;
    int gr = r0g + r - PAD, gc = cc - PAD;
    float val = 0.f;
    if (gr >= 0 && gr < 64 && gc >= 0 && gc < 64) val = vrow[gr * 64 + gc];
    vh[r * VH_PITCH + cc] = val;
  }
  __syncthreads();

  int col = t & 63, wid = t >> 6;
  int rb = wid * 8;                         // wave's first output row within tile
  v2f lp2[8][8];                            // [kpair][row] -- registers ONLY
  #pragma unroll
  for (int j = 0; j < 8; j++)
    #pragma unroll
    for (int i = 0; i < 8; i++) { lp2[j][i].x = 0.f; lp2[j][i].y = 0.f; }

  #pragma unroll 1
  for (int kx = 0; kx < 23; kx++) {
    const float* wp = vh + rb * VH_PITCH + (col + kx);
    float w[8];
    #pragma unroll
    for (int i = 0; i < 8; i++) w[i] = wp[i * VH_PITCH];
    #pragma unroll
    for (int ky = 0; ky < 23; ky++) {
      const uint4* ep = (const uint4*)&ebf[(ky * 23 + kx) * 8];
      uint4 ea = ep[0];
      uint4 eb = ep[1];
      float wn = (ky < 22) ? wp[(8 + ky) * VH_PITCH] : 0.f;   // prefetch next row
      v2f e2[8];
      e2[0].x = __uint_as_float(ea.x << 16); e2[0].y = __uint_as_float(ea.x & 0xffff0000u);
      e2[1].x = __uint_as_float(ea.y << 16); e2[1].y = __uint_as_float(ea.y & 0xffff0000u);
      e2[2].x = __uint_as_float(ea.z << 16); e2[2].y = __uint_as_float(ea.z & 0xffff0000u);
      e2[3].x = __uint_as_float(ea.w << 16); e2[3].y = __uint_as_float(ea.w & 0xffff0000u);
      e2[4].x = __uint_as_float(eb.x << 16); e2[4].y = __uint_as_float(eb.x & 0xffff0000u);
      e2[5].x = __uint_as_float(eb.y << 16); e2[5].y = __uint_as_float(eb.y & 0xffff0000u);
      e2[6].x = __uint_as_float(eb.z << 16); e2[6].y = __uint_as_float(eb.z & 0xffff0000u);
      e2[7].x = __uint_as_float(eb.w << 16); e2[7].y = __uint_as_float(eb.w & 0xffff0000u);
      #pragma unroll
      for (int i = 0; i < 8; i++) {
        v2f wpair; wpair.x = w[i]; wpair.y = w[i];
        #pragma unroll
        for (int j = 0; j < 8; j++) lp2[j][i] += e2[j] * wpair;
      }
      #pragma unroll
      for (int i = 0; i < 7; i++) w[i] = w[i + 1];
      w[7] = wn;
    }
  }

  float lcv[16];
  #pragma unroll
  for (int k = 0; k < 16; k++) lcv[k] = lc[((size_t)b * 16 + k) * 64 + v];  // uniform
  const float* qbp = proj + (size_t)b * NCH * NPIX;
  float* ob = out + (size_t)b * 256 * NPIX;
  #pragma unroll
  for (int i = 0; i < 8; i++) {                  // FULL unroll: lp2 indices constant
    int n = (r0g + rb + i) * 64 + col;
    float lam[16];
    #pragma unroll
    for (int j = 0; j < 8; j++) {
      lam[2 * j]     = lp2[j][i].x + lcv[2 * j];
      lam[2 * j + 1] = lp2[j][i].y + lcv[2 * j + 1];
    }
    float y0 = 0.f, y1 = 0.f, y2 = 0.f, y3 = 0.f;
    #pragma unroll
    for (int k = 0; k < 16; k++) {
      float mz = lam[k];
      y0 += qbp[(size_t)(0 * 16 + k) * NPIX + n] * mz;
      y1 += qbp[(size_t)(1 * 16 + k) * NPIX + n] * mz;
      y2 += qbp[(size_t)(2 * 16 + k) * NPIX + n] * mz;
      y3 += qbp[(size_t)(3 * 16 + k) * NPIX + n] * mz;
    }
    ob[(size_t)(0 * 64 + v) * NPIX + n] = y0;
    ob[(size_t)(1 * 64 + v) * NPIX + n] = y1;
    ob[(size_t)(2 * 64 + v) * NPIX + n] = y2;
    ob[(size_t)(3 * 64 + v) * NPIX + n] = y3;
  }
}

extern "C" void kernel_launch(void* const* d_in, const int* in_sizes, int n_in,
                              void* d_out, int out_size, void* d_ws, size_t ws_size,
                              hipStream_t stream) {
  const float* x    = (const float*)d_in[0];
  const float* Wq   = (const float*)d_in[1];
  const float* qg   = (const float*)d_in[2];
  const float* qbta = (const float*)d_in[3];
  const float* qm   = (const float*)d_in[4];
  const float* qv   = (const float*)d_in[5];
  const float* Wk   = (const float*)d_in[6];
  const float* Wv   = (const float*)d_in[7];
  const float* vg   = (const float*)d_in[8];
  const float* vb   = (const float*)d_in[9];
  const float* vm   = (const float*)d_in[10];
  const float* vvar = (const float*)d_in[11];
  const float* emb  = (const float*)d_in[12];
  float* ws   = (float*)d_ws;
  float* Wt   = ws + WP_OFF;
  float* bp   = ws + BIAS_OFF;
  float* proj = ws + PROJ_OFF;
  float* rmax = ws + RMAX_OFF;
  float* rsc  = ws + RSC_OFF;
  float* lcw  = ws + LC_OFF;
  float* etw  = ws + ET_OFF;
  float* out  = (float*)d_out;

  hipLaunchKernelGGL(k_wfold, dim3(144), dim3(256), 0, stream,
                     Wq, qg, qbta, qm, qv, Wk, Wv, vg, vb, vm, vvar, Wt, bp);
  hipLaunchKernelGGL(k_etrans, dim3(34), dim3(256), 0, stream, emb, etw);
  hipMemsetAsync(lcw, 0, 16 * 64 * B * sizeof(float), stream);
  hipLaunchKernelGGL(k_proj, dim3(3, 16, 8), dim3(256), 0, stream, x, Wt, bp, proj);
  hipLaunchKernelGGL(k_softstat, dim3(16, 8), dim3(256), 0, stream, proj, rmax, rsc);
  hipLaunchKernelGGL(k_lambda_c, dim3(16, 8, 8), dim3(256), 0, stream, proj, rmax, rsc, lcw);
  hipLaunchKernelGGL(k_conv_fused, dim3(64, 2, 8), dim3(256), 0, stream, proj, etw, lcw, out);
}

// Round 7
// 510.116 us; speedup vs baseline: 19.3238x; 1.5208x over previous
//
#include <hip/hip_runtime.h>

typedef __attribute__((ext_vector_type(8))) short bf16x8;
typedef __attribute__((ext_vector_type(4))) float f32x4;

#define EPS 1e-5f
#define B 8
#define C 256
#define NPIX 4096      // 64*64
#define NCH 144        // rows: 0..63 q_bn, 64..127 v_bn, 128..143 kf(raw)
#define ROW_V 64
#define ROW_KF 128
#define PAD 11

// workspace layout (float offsets)
#define WP_OFF    0u          // Wt transposed: 256*144 = 36864
#define BIAS_OFF  36864u      // 144
#define PROJ_OFF  37120u      // 8*144*4096 = 4718592
#define RMAX_OFF  4755712u    // 128
#define RSC_OFF   4755840u    // 128
#define LC_OFF    4755968u    // 8*16*64 = 8192
#define ET_OFF    4764160u    // E shifted variants: 8*23*64*8 ushort = 47104 floats

// ---------------- 1) fold BN into transposed projection weights Wt[c][144] ----------
__global__ __launch_bounds__(256) void k_wfold(
    const float* __restrict__ Wq, const float* __restrict__ qg, const float* __restrict__ qb,
    const float* __restrict__ qm, const float* __restrict__ qv,
    const float* __restrict__ Wk, const float* __restrict__ Wv,
    const float* __restrict__ vg, const float* __restrict__ vb,
    const float* __restrict__ vm, const float* __restrict__ vvar,
    float* __restrict__ Wt, float* __restrict__ biasp) {
  int o = blockIdx.x;   // 0..143
  int t = threadIdx.x;  // 0..255 = c
  const float* src; float s, bias;
  if (o < 64) {
    s = qg[o] * rsqrtf(qv[o] + EPS); bias = qb[o] - qm[o] * s; src = Wq + o * C;
  } else if (o < 128) {
    int i = o - 64;
    s = vg[i] * rsqrtf(vvar[i] + EPS); bias = vb[i] - vm[i] * s; src = Wv + i * C;
  } else {
    int i = o - 128; s = 1.f; bias = 0.f; src = Wk + i * C;
  }
  Wt[t * NCH + o] = src[t] * s;
  if (t == 0) biasp[o] = bias;
}

// ---------------- 1b) build 8 shifted bf16 filter variants ----------
// etw[s][dy][lane][jj]: filter f=lane&15, octet q=lane>>4, u=q*8+jj, dx=u-s;
// value = emb[f,dy,dx] if 0<=dx<23 else 0.  (A-fragment-ready layout)
// The shift s lives ONLY here (R6 bug: it was also in the halo -> double shift).
__global__ __launch_bounds__(256) void k_eprep(
    const float* __restrict__ emb, ushort* __restrict__ etw) {
  int i = blockIdx.x * 256 + threadIdx.x;   // 0..94207
  int s = i / 11776;
  int r = i % 11776;
  int dy = r / 512;
  int l = (r / 8) % 64;
  int jj = r % 8;
  int f = l & 15, q = l >> 4;
  int dx = q * 8 + jj - s;
  float val = (dx >= 0 && dx < 23) ? emb[f * 529 + dy * 23 + dx] : 0.f;
  unsigned u = __float_as_uint(val);
  etw[i] = (ushort)((u + 0x7fffu + ((u >> 16) & 1u)) >> 16);
}

// ---------------- 2) projection GEMM ----------
__global__ __launch_bounds__(256) void k_proj(
    const float* __restrict__ x, const float* __restrict__ Wt,
    const float* __restrict__ biasp, float* __restrict__ proj) {
  int g = blockIdx.x;     // 0..2 (48 ch each)
  int tile = blockIdx.y;  // 0..15
  int b = blockIdx.z;
  int t = threadIdx.x;
  int px = tile * 256 + t;
  const float* xb = x + (size_t)b * C * NPIX + px;
  float acc[48];
  #pragma unroll
  for (int i = 0; i < 48; i++) acc[i] = 0.f;
  #pragma unroll 2
  for (int c = 0; c < C; c++) {
    float xv = xb[(size_t)c * NPIX];
    const float* wrow = Wt + c * NCH + g * 48;
    #pragma unroll
    for (int i = 0; i < 48; i++) acc[i] += xv * wrow[i];
  }
  float* ob = proj + ((size_t)b * NCH + g * 48) * NPIX + px;
  #pragma unroll
  for (int i = 0; i < 48; i++) ob[(size_t)i * NPIX] = acc[i] + biasp[g * 48 + i];
}

// ---------------- 3) softmax row stats ----------
__global__ __launch_bounds__(256) void k_softstat(
    const float* __restrict__ proj, float* __restrict__ rmax, float* __restrict__ rsc) {
  int k = blockIdx.x, b = blockIdx.y, t = threadIdx.x;
  const float* row = proj + ((size_t)b * NCH + ROW_KF + k) * NPIX;
  __shared__ float sd[256];
  float m = -1e30f;
  for (int n = t; n < NPIX; n += 256) m = fmaxf(m, row[n]);
  sd[t] = m; __syncthreads();
  for (int s = 128; s > 0; s >>= 1) { if (t < s) sd[t] = fmaxf(sd[t], sd[t + s]); __syncthreads(); }
  m = sd[0]; __syncthreads();
  float sum = 0.f;
  for (int n = t; n < NPIX; n += 256) sum += __expf(row[n] - m);
  sd[t] = sum; __syncthreads();
  for (int s = 128; s > 0; s >>= 1) { if (t < s) sd[t] += sd[t + s]; __syncthreads(); }
  if (t == 0) { rmax[b * 16 + k] = m; rsc[b * 16 + k] = 1.f / sd[0]; }
}

// ---------------- 4) lambda_c partial: atomicAdd into zeroed lc ----------
__global__ __launch_bounds__(256) void k_lambda_c(
    const float* __restrict__ proj, const float* __restrict__ rmax,
    const float* __restrict__ rsc, float* __restrict__ lc) {
  int k = blockIdx.x, chunk = blockIdx.y, b = blockIdx.z, t = threadIdx.x;
  const float* row = proj + ((size_t)b * NCH + ROW_KF + k) * NPIX;
  const float* vbase = proj + ((size_t)b * NCH + ROW_V) * NPIX;
  float m = rmax[b * 16 + k], sc = rsc[b * 16 + k];
  float acc[64];
  #pragma unroll
  for (int i = 0; i < 64; i++) acc[i] = 0.f;
  for (int it = 0; it < 2; ++it) {
    int n = chunk * 512 + it * 256 + t;
    float p = __expf(row[n] - m) * sc;
    #pragma unroll
    for (int vv = 0; vv < 64; vv++) acc[vv] += p * vbase[(size_t)vv * NPIX + n];
  }
  int lane = t & 63, wid = t >> 6;
  float keep = 0.f;
  #pragma unroll
  for (int vv = 0; vv < 64; vv++) {
    float s = acc[vv];
    #pragma unroll
    for (int off = 32; off > 0; off >>= 1) s += __shfl_xor(s, off);
    if (lane == vv) keep = s;
  }
  __shared__ float sh[4 * 64];
  sh[wid * 64 + lane] = keep;
  __syncthreads();
  if (t < 64) {
    float val = sh[t] + sh[64 + t] + sh[128 + t] + sh[192 + t];
    atomicAdd(&lc[((size_t)b * 16 + k) * 64 + t], val);
  }
}

// ---------------- 5) MFMA implicit-im2col conv + fused epilogue ----------
// Block = (s, v, b): pixels x ≡ s (mod 8), all 64 rows, one v-slice.
// MFMA 16x16x32 bf16: M=16 filters (A=E_s), N=16 pixels (2 rows x 8 strided x),
// K=32 taps = one kernel row dy (u=0..31; dx=u-s folded into E_s ONLY).
// Pixel pc=8g+s, tap dx=u-s => column pc+dx-11 = 8g+u-11: s cancels, halo is
// shift-free and the B-gather is ONE aligned ds_read_b128 per lane.
// C-layout: col(lane&15)=pixel, row((lane>>4)*4+reg)=filter.
__global__ __launch_bounds__(256, 2) void k_conv_mfma(
    const float* __restrict__ proj, const ushort* __restrict__ etw,
    const float* __restrict__ lc, float* __restrict__ out) {
  int s = blockIdx.x;      // 0..7
  int v = blockIdx.y;      // 0..63
  int b = blockIdx.z;
  int t = threadIdx.x;
  __shared__ __align__(16) ushort vh[86 * 88];      // 15136 B halo bf16
  __shared__ __align__(16) ushort elds[23 * 64 * 8]; // 23552 B E_s chunks

  // stage E_s (coalesced 16B copies)
  {
    const uint4* src = (const uint4*)etw + s * 1472;
    uint4* dst = (uint4*)elds;
    for (int i = t; i < 1472; i += 256) dst[i] = src[i];
  }
  // stage V halo: halo(hr,hc) = V[hr-11][hc-11] or 0   (NO s shift here)
  const float* vrow = proj + ((size_t)b * NCH + ROW_V + v) * NPIX;
  for (int i = t; i < 86 * 88; i += 256) {
    int hr = i / 88, hc = i % 88;
    int ir = hr - 11, ic = hc - 11;
    float val = (ir >= 0 && ir < 64 && ic >= 0 && ic < 64) ? vrow[ir * 64 + ic] : 0.f;
    unsigned u = __float_as_uint(val);
    vh[i] = (ushort)((u + 0x7fffu + ((u >> 16) & 1u)) >> 16);
  }
  __syncthreads();

  int lane = t & 63, w = t >> 6;
  int n_ = lane & 15, q = lane >> 4;
  int rn = n_ >> 3, g = n_ & 7;

  f32x4 acc[8];
  #pragma unroll
  for (int i = 0; i < 8; i++) acc[i] = (f32x4)(0.f);

  const bf16x8* vh8 = (const bf16x8*)vh;
  const bf16x8* e8 = (const bf16x8*)elds;
  // bf16x8-unit index: (hr*88 + 8g + 8q)/8 = hr*11 + g + q; hr = w*16 + 2*tt + rn + dy
  int baseA = (w * 16 + rn) * 11 + g + q;
  #pragma unroll 1
  for (int dy = 0; dy < 23; dy++) {
    bf16x8 ef = e8[dy * 64 + lane];
    int idx = baseA + dy * 11;
    #pragma unroll
    for (int tt = 0; tt < 8; tt++) {
      bf16x8 bf = vh8[idx + 22 * tt];
      acc[tt] = __builtin_amdgcn_mfma_f32_16x16x32_bf16(ef, bf, acc[tt], 0, 0, 0);
    }
  }

  // epilogue: lam = lp + lc; y[h] = sum_k q[h,k,p]*lam[k]; 4-lane butterfly over k-groups
  float lcv[4];
  #pragma unroll
  for (int r = 0; r < 4; r++) lcv[r] = lc[((size_t)b * 16 + q * 4 + r) * 64 + v];
  const float* qbp = proj + (size_t)b * NCH * NPIX;
  float* ob = out + (size_t)b * 256 * NPIX;
  #pragma unroll
  for (int tt = 0; tt < 8; tt++) {
    int p = (w * 16 + 2 * tt + rn) * 64 + 8 * g + s;
    float lam[4];
    #pragma unroll
    for (int r = 0; r < 4; r++) lam[r] = acc[tt][r] + lcv[r];
    float y[4];
    #pragma unroll
    for (int h = 0; h < 4; h++) {
      float a = 0.f;
      #pragma unroll
      for (int r = 0; r < 4; r++)
        a += qbp[(size_t)(h * 16 + q * 4 + r) * NPIX + p] * lam[r];
      y[h] = a;
    }
    #pragma unroll
    for (int h = 0; h < 4; h++) {
      y[h] += __shfl_xor(y[h], 16);
      y[h] += __shfl_xor(y[h], 32);
    }
    if (q == 0) {
      #pragma unroll
      for (int h = 0; h < 4; h++) ob[(size_t)(h * 64 + v) * NPIX + p] = y[h];
    }
  }
}

extern "C" void kernel_launch(void* const* d_in, const int* in_sizes, int n_in,
                              void* d_out, int out_size, void* d_ws, size_t ws_size,
                              hipStream_t stream) {
  const float* x    = (const float*)d_in[0];
  const float* Wq   = (const float*)d_in[1];
  const float* qg   = (const float*)d_in[2];
  const float* qbta = (const float*)d_in[3];
  const float* qm   = (const float*)d_in[4];
  const float* qv   = (const float*)d_in[5];
  const float* Wk   = (const float*)d_in[6];
  const float* Wv   = (const float*)d_in[7];
  const float* vg   = (const float*)d_in[8];
  const float* vb   = (const float*)d_in[9];
  const float* vm   = (const float*)d_in[10];
  const float* vvar = (const float*)d_in[11];
  const float* emb  = (const float*)d_in[12];
  float* ws   = (float*)d_ws;
  float* Wt   = ws + WP_OFF;
  float* bp   = ws + BIAS_OFF;
  float* proj = ws + PROJ_OFF;
  float* rmax = ws + RMAX_OFF;
  float* rsc  = ws + RSC_OFF;
  float* lcw  = ws + LC_OFF;
  ushort* etw = (ushort*)(ws + ET_OFF);
  float* out  = (float*)d_out;

  hipLaunchKernelGGL(k_wfold, dim3(144), dim3(256), 0, stream,
                     Wq, qg, qbta, qm, qv, Wk, Wv, vg, vb, vm, vvar, Wt, bp);
  hipLaunchKernelGGL(k_eprep, dim3(368), dim3(256), 0, stream, emb, etw);
  hipMemsetAsync(lcw, 0, 16 * 64 * B * sizeof(float), stream);
  hipLaunchKernelGGL(k_proj, dim3(3, 16, 8), dim3(256), 0, stream, x, Wt, bp, proj);
  hipLaunchKernelGGL(k_softstat, dim3(16, 8), dim3(256), 0, stream, proj, rmax, rsc);
  hipLaunchKernelGGL(k_lambda_c, dim3(16, 8, 8), dim3(256), 0, stream, proj, rmax, rsc, lcw);
  hipLaunchKernelGGL(k_conv_mfma, dim3(8, 64, 8), dim3(256), 0, stream, proj, etw, lcw, out);
}

// Round 8
// 318.725 us; speedup vs baseline: 30.9276x; 1.6005x over previous
//
#include <hip/hip_runtime.h>

typedef __attribute__((ext_vector_type(8))) short bf16x8;
typedef __attribute__((ext_vector_type(4))) float f32x4;

#define EPS 1e-5f
#define B 8
#define C 256
#define NPIX 4096      // 64*64
#define NCH 144        // rows: 0..63 q_bn, 64..127 v_bn, 128..143 kf(raw)
#define ROW_V 64
#define ROW_KF 128
#define PAD 11

// workspace layout (float offsets)
#define WP_OFF    0u          // Wt transposed: 256*144 = 36864
#define BIAS_OFF  36864u      // 144
#define PROJ_OFF  37120u      // 8*144*4096 = 4718592
#define RMAX_OFF  4755712u    // 128
#define RSC_OFF   4755840u    // 128
#define LC_OFF    4755968u    // 8*16*64 = 8192
#define ET_OFF    4764160u    // E variants: 94208 ushort = 47104 floats
#define QT_OFF    4811264u    // qT: 8*64*4096 = 2097152
#define OUTT_OFF  6908416u    // outT: 8*256*4096 = 8388608 (end 15297024 floats)
#define WS_NEED_QT    6908416u
#define WS_NEED_FULL  15297024u

// ---------------- 1) fold BN into transposed projection weights Wt[c][144] ----------
__global__ __launch_bounds__(256) void k_wfold(
    const float* __restrict__ Wq, const float* __restrict__ qg, const float* __restrict__ qb,
    const float* __restrict__ qm, const float* __restrict__ qv,
    const float* __restrict__ Wk, const float* __restrict__ Wv,
    const float* __restrict__ vg, const float* __restrict__ vb,
    const float* __restrict__ vm, const float* __restrict__ vvar,
    float* __restrict__ Wt, float* __restrict__ biasp) {
  int o = blockIdx.x;   // 0..143
  int t = threadIdx.x;  // 0..255 = c
  const float* src; float s, bias;
  if (o < 64) {
    s = qg[o] * rsqrtf(qv[o] + EPS); bias = qb[o] - qm[o] * s; src = Wq + o * C;
  } else if (o < 128) {
    int i = o - 64;
    s = vg[i] * rsqrtf(vvar[i] + EPS); bias = vb[i] - vm[i] * s; src = Wv + i * C;
  } else {
    int i = o - 128; s = 1.f; bias = 0.f; src = Wk + i * C;
  }
  Wt[t * NCH + o] = src[t] * s;
  if (t == 0) biasp[o] = bias;
}

// ---------------- 1b) build 8 shifted bf16 filter variants (shift lives ONLY here) ----
__global__ __launch_bounds__(256) void k_eprep(
    const float* __restrict__ emb, ushort* __restrict__ etw) {
  int i = blockIdx.x * 256 + threadIdx.x;   // 0..94207
  int s = i / 11776;
  int r = i % 11776;
  int dy = r / 512;
  int l = (r / 8) % 64;
  int jj = r % 8;
  int f = l & 15, q = l >> 4;
  int dx = q * 8 + jj - s;
  float val = (dx >= 0 && dx < 23) ? emb[f * 529 + dy * 23 + dx] : 0.f;
  unsigned u = __float_as_uint(val);
  etw[i] = (ushort)((u + 0x7fffu + ((u >> 16) & 1u)) >> 16);
}

// ---------------- 2) projection GEMM: 4 groups of 36 ch ----------
__global__ __launch_bounds__(256) void k_proj(
    const float* __restrict__ x, const float* __restrict__ Wt,
    const float* __restrict__ biasp, float* __restrict__ proj) {
  int g = blockIdx.x;     // 0..3 (36 ch each)
  int tile = blockIdx.y;  // 0..15
  int b = blockIdx.z;
  int t = threadIdx.x;
  int px = tile * 256 + t;
  const float* xb = x + (size_t)b * C * NPIX + px;
  float acc[36];
  #pragma unroll
  for (int i = 0; i < 36; i++) acc[i] = 0.f;
  #pragma unroll 2
  for (int c = 0; c < C; c++) {
    float xv = xb[(size_t)c * NPIX];
    const float* wrow = Wt + c * NCH + g * 36;   // uniform -> s_load
    #pragma unroll
    for (int i = 0; i < 36; i++) acc[i] += xv * wrow[i];
  }
  float* ob = proj + ((size_t)b * NCH + g * 36) * NPIX + px;
  #pragma unroll
  for (int i = 0; i < 36; i++) ob[(size_t)i * NPIX] = acc[i] + biasp[g * 36 + i];
}

// ---------------- 2b) transpose q rows: proj[b][ch][p] -> qT[b][ch][s*512+i] ----------
// p = row*64 + 8g + s ; i = row*8 + g. LDS pad p' = p + (p>>3): conflict-free.
__global__ __launch_bounds__(256) void k_qtrans(
    const float* __restrict__ proj, float* __restrict__ qT) {
  int ch = blockIdx.x, b = blockIdx.y, t = threadIdx.x;
  __shared__ float buf[4608];
  const float* src = proj + ((size_t)b * NCH + ch) * NPIX;
  for (int it = 0; it < 16; it++) {
    int p = it * 256 + t;
    buf[p + (p >> 3)] = src[p];
  }
  __syncthreads();
  float* dst = qT + ((size_t)b * 64 + ch) * NPIX;
  for (int it = 0; it < 16; it++) {
    int idx = it * 256 + t;           // s*512 + i
    int s = idx >> 9, i = idx & 511;
    int p = (i >> 3) * 64 + (i & 7) * 8 + s;
    dst[idx] = buf[p + (p >> 3)];
  }
}

// ---------------- 3) softmax row stats ----------
__global__ __launch_bounds__(256) void k_softstat(
    const float* __restrict__ proj, float* __restrict__ rmax, float* __restrict__ rsc) {
  int k = blockIdx.x, b = blockIdx.y, t = threadIdx.x;
  const float* row = proj + ((size_t)b * NCH + ROW_KF + k) * NPIX;
  __shared__ float sd[256];
  float m = -1e30f;
  for (int n = t; n < NPIX; n += 256) m = fmaxf(m, row[n]);
  sd[t] = m; __syncthreads();
  for (int s = 128; s > 0; s >>= 1) { if (t < s) sd[t] = fmaxf(sd[t], sd[t + s]); __syncthreads(); }
  m = sd[0]; __syncthreads();
  float sum = 0.f;
  for (int n = t; n < NPIX; n += 256) sum += __expf(row[n] - m);
  sd[t] = sum; __syncthreads();
  for (int s = 128; s > 0; s >>= 1) { if (t < s) sd[t] += sd[t + s]; __syncthreads(); }
  if (t == 0) { rmax[b * 16 + k] = m; rsc[b * 16 + k] = 1.f / sd[0]; }
}

// ---------------- 4) lambda_c partial: atomicAdd into zeroed lc ----------
__global__ __launch_bounds__(256) void k_lambda_c(
    const float* __restrict__ proj, const float* __restrict__ rmax,
    const float* __restrict__ rsc, float* __restrict__ lc) {
  int k = blockIdx.x, chunk = blockIdx.y, b = blockIdx.z, t = threadIdx.x;
  const float* row = proj + ((size_t)b * NCH + ROW_KF + k) * NPIX;
  const float* vbase = proj + ((size_t)b * NCH + ROW_V) * NPIX;
  float m = rmax[b * 16 + k], sc = rsc[b * 16 + k];
  float acc[64];
  #pragma unroll
  for (int i = 0; i < 64; i++) acc[i] = 0.f;
  for (int it = 0; it < 2; ++it) {
    int n = chunk * 512 + it * 256 + t;
    float p = __expf(row[n] - m) * sc;
    #pragma unroll
    for (int vv = 0; vv < 64; vv++) acc[vv] += p * vbase[(size_t)vv * NPIX + n];
  }
  int lane = t & 63, wid = t >> 6;
  float keep = 0.f;
  #pragma unroll
  for (int vv = 0; vv < 64; vv++) {
    float s = acc[vv];
    #pragma unroll
    for (int off = 32; off > 0; off >>= 1) s += __shfl_xor(s, off);
    if (lane == vv) keep = s;
  }
  __shared__ float sh[4 * 64];
  sh[wid * 64 + lane] = keep;
  __syncthreads();
  if (t < 64) {
    float val = sh[t] + sh[64 + t] + sh[128 + t] + sh[192 + t];
    atomicAdd(&lc[((size_t)b * 16 + k) * 64 + t], val);
  }
}

// ---------------- 5) MFMA implicit-im2col conv + fused epilogue ----------
// mode 2: q from qT (coalesced), store outT (dense) ; mode 1: qT reads, direct
// scattered out stores ; mode 0: R7 behavior (proj q, scattered stores).
__global__ __launch_bounds__(256, 2) void k_conv_mfma(
    const float* __restrict__ proj, const ushort* __restrict__ etw,
    const float* __restrict__ qT, const float* __restrict__ lc,
    float* __restrict__ outT, float* __restrict__ out, int mode) {
  int s = blockIdx.x;      // 0..7
  int v = blockIdx.y;      // 0..63
  int b = blockIdx.z;
  int t = threadIdx.x;
  __shared__ __align__(16) ushort vh[86 * 88];       // 15136 B halo bf16
  __shared__ __align__(16) ushort elds[23 * 64 * 8]; // 23552 B E_s chunks

  {
    const uint4* src = (const uint4*)etw + s * 1472;
    uint4* dst = (uint4*)elds;
    for (int i = t; i < 1472; i += 256) dst[i] = src[i];
  }
  const float* vrow = proj + ((size_t)b * NCH + ROW_V + v) * NPIX;
  for (int i = t; i < 86 * 88; i += 256) {
    int hr = i / 88, hc = i % 88;
    int ir = hr - 11, ic = hc - 11;
    float val = (ir >= 0 && ir < 64 && ic >= 0 && ic < 64) ? vrow[ir * 64 + ic] : 0.f;
    unsigned u = __float_as_uint(val);
    vh[i] = (ushort)((u + 0x7fffu + ((u >> 16) & 1u)) >> 16);
  }
  __syncthreads();

  int lane = t & 63, w = t >> 6;
  int n_ = lane & 15, q = lane >> 4;
  int rn = n_ >> 3, g = n_ & 7;

  f32x4 acc[8];
  #pragma unroll
  for (int i = 0; i < 8; i++) acc[i] = (f32x4)(0.f);

  const bf16x8* vh8 = (const bf16x8*)vh;
  const bf16x8* e8 = (const bf16x8*)elds;
  int baseA = (w * 16 + rn) * 11 + g + q;
  #pragma unroll 1
  for (int dy = 0; dy < 23; dy++) {
    bf16x8 ef = e8[dy * 64 + lane];
    int idx = baseA + dy * 11;
    #pragma unroll
    for (int tt = 0; tt < 8; tt++) {
      bf16x8 bf = vh8[idx + 22 * tt];
      acc[tt] = __builtin_amdgcn_mfma_f32_16x16x32_bf16(ef, bf, acc[tt], 0, 0, 0);
    }
  }

  float lcv[4];
  #pragma unroll
  for (int r = 0; r < 4; r++) lcv[r] = lc[((size_t)b * 16 + q * 4 + r) * 64 + v];

  if (mode != 0) {
    const float* qTb = qT + (size_t)b * 64 * NPIX;
    float* obT = outT + (size_t)b * 256 * NPIX;
    float* ob = out + (size_t)b * 256 * NPIX;
    #pragma unroll
    for (int tt = 0; tt < 8; tt++) {
      int row = w * 16 + 2 * tt + rn;
      int io = s * 512 + row * 8 + g;              // qT / outT index (coalesced)
      float lam[4];
      #pragma unroll
      for (int r = 0; r < 4; r++) lam[r] = acc[tt][r] + lcv[r];
      float y[4];
      #pragma unroll
      for (int h = 0; h < 4; h++) {
        float a = 0.f;
        #pragma unroll
        for (int r = 0; r < 4; r++)
          a += qTb[(size_t)(h * 16 + q * 4 + r) * NPIX + io] * lam[r];
        y[h] = a;
      }
      #pragma unroll
      for (int h = 0; h < 4; h++) {
        y[h] += __shfl_xor(y[h], 16);
        y[h] += __shfl_xor(y[h], 32);
      }
      if (q == 0) {
        if (mode == 2) {
          #pragma unroll
          for (int h = 0; h < 4; h++) obT[(size_t)(h * 64 + v) * NPIX + io] = y[h];
        } else {
          int p = row * 64 + 8 * g + s;
          #pragma unroll
          for (int h = 0; h < 4; h++) ob[(size_t)(h * 64 + v) * NPIX + p] = y[h];
        }
      }
    }
  } else {
    const float* qbp = proj + (size_t)b * NCH * NPIX;
    float* ob = out + (size_t)b * 256 * NPIX;
    #pragma unroll
    for (int tt = 0; tt < 8; tt++) {
      int p = (w * 16 + 2 * tt + rn) * 64 + 8 * g + s;
      float lam[4];
      #pragma unroll
      for (int r = 0; r < 4; r++) lam[r] = acc[tt][r] + lcv[r];
      float y[4];
      #pragma unroll
      for (int h = 0; h < 4; h++) {
        float a = 0.f;
        #pragma unroll
        for (int r = 0; r < 4; r++)
          a += qbp[(size_t)(h * 16 + q * 4 + r) * NPIX + p] * lam[r];
        y[h] = a;
      }
      #pragma unroll
      for (int h = 0; h < 4; h++) {
        y[h] += __shfl_xor(y[h], 16);
        y[h] += __shfl_xor(y[h], 32);
      }
      if (q == 0) {
        #pragma unroll
        for (int h = 0; h < 4; h++) ob[(size_t)(h * 64 + v) * NPIX + p] = y[h];
      }
    }
  }
}

// ---------------- 6) un-transpose: outT[b][ch][s*512+i] -> out[b][ch][p] ----------
__global__ __launch_bounds__(256) void k_outtrans(
    const float* __restrict__ outT, float* __restrict__ out) {
  int ch = blockIdx.x, b = blockIdx.y, t = threadIdx.x;
  __shared__ float buf[4608];
  const float* src = outT + ((size_t)b * 256 + ch) * NPIX;
  for (int it = 0; it < 16; it++) {
    int idx = it * 256 + t;           // s*512 + i
    int s = idx >> 9, i = idx & 511;
    int p = (i >> 3) * 64 + (i & 7) * 8 + s;
    buf[p + (p >> 3)] = src[idx];
  }
  __syncthreads();
  float* dst = out + ((size_t)b * 256 + ch) * NPIX;
  for (int it = 0; it < 16; it++) {
    int p = it * 256 + t;
    dst[p] = buf[p + (p >> 3)];
  }
}

extern "C" void kernel_launch(void* const* d_in, const int* in_sizes, int n_in,
                              void* d_out, int out_size, void* d_ws, size_t ws_size,
                              hipStream_t stream) {
  const float* x    = (const float*)d_in[0];
  const float* Wq   = (const float*)d_in[1];
  const float* qg   = (const float*)d_in[2];
  const float* qbta = (const float*)d_in[3];
  const float* qm   = (const float*)d_in[4];
  const float* qv   = (const float*)d_in[5];
  const float* Wk   = (const float*)d_in[6];
  const float* Wv   = (const float*)d_in[7];
  const float* vg   = (const float*)d_in[8];
  const float* vb   = (const float*)d_in[9];
  const float* vm   = (const float*)d_in[10];
  const float* vvar = (const float*)d_in[11];
  const float* emb  = (const float*)d_in[12];
  float* ws   = (float*)d_ws;
  float* Wt   = ws + WP_OFF;
  float* bp   = ws + BIAS_OFF;
  float* proj = ws + PROJ_OFF;
  float* rmax = ws + RMAX_OFF;
  float* rsc  = ws + RSC_OFF;
  float* lcw  = ws + LC_OFF;
  ushort* etw = (ushort*)(ws + ET_OFF);
  float* qT   = ws + QT_OFF;
  float* outT = ws + OUTT_OFF;
  float* out  = (float*)d_out;

  size_t wsf = ws_size / sizeof(float);
  int mode = (wsf >= WS_NEED_FULL) ? 2 : ((wsf >= WS_NEED_QT) ? 1 : 0);

  hipLaunchKernelGGL(k_wfold, dim3(144), dim3(256), 0, stream,
                     Wq, qg, qbta, qm, qv, Wk, Wv, vg, vb, vm, vvar, Wt, bp);
  hipLaunchKernelGGL(k_eprep, dim3(368), dim3(256), 0, stream, emb, etw);
  hipMemsetAsync(lcw, 0, 16 * 64 * B * sizeof(float), stream);
  hipLaunchKernelGGL(k_proj, dim3(4, 16, 8), dim3(256), 0, stream, x, Wt, bp, proj);
  if (mode >= 1)
    hipLaunchKernelGGL(k_qtrans, dim3(64, 8), dim3(256), 0, stream, proj, qT);
  hipLaunchKernelGGL(k_softstat, dim3(16, 8), dim3(256), 0, stream, proj, rmax, rsc);
  hipLaunchKernelGGL(k_lambda_c, dim3(16, 8, 8), dim3(256), 0, stream, proj, rmax, rsc, lcw);
  hipLaunchKernelGGL(k_conv_mfma, dim3(8, 64, 8), dim3(256), 0, stream,
                     proj, etw, qT, lcw, outT, out, mode);
  if (mode == 2)
    hipLaunchKernelGGL(k_outtrans, dim3(256, 8), dim3(256), 0, stream, outT, out);
}